// Round 12
// baseline (119.808 us; speedup 1.0000x reference)
//
#include <hip/hip_runtime.h>
#include <math.h>

#define NPTS   2048      // N
#define LFEAT  56        // C*L
#define HFEAT  128       // H
#define HALFW  8
#define NEIGH  17
#define FROWS  16        // rows per feat block
#define BR     32        // rows per attn block (chunk within one batch)
#define BAND   48        // BR + 2*HALFW
#define LDW    132       // 128 + 4 floats pad

// ---------------------------------------------------------------------------
// Kernel A (v3): conv + BN + LeakyReLU for BOTH sources. No LDS.
// Thread owns h: W column in 56 VGPRs. x row read as same-address float4
// global loads (1 L1 line fetch + broadcast per load, VMEM pipe only).
// One row at a time, two FMA chains (even/odd q) for ILP.
// Row space: rows [0, R) = input, rows [R, 2R) = state_memory, R = B*N.
// ---------------------------------------------------------------------------
__global__ __launch_bounds__(128) void feat_kernel(
    const float* __restrict__ x_in, const float* __restrict__ x_mem,
    const float* __restrict__ conv_w, const float* __restrict__ conv_b,
    const float* __restrict__ gamma,  const float* __restrict__ beta,
    const float* __restrict__ bmean,  const float* __restrict__ bvar,
    float* __restrict__ f_all, int R)
{
    const int h    = threadIdx.x;           // 0..127
    const int base = blockIdx.x * FROWS;    // uniform

    const float* src;
    int srow;
    if (base < R) { src = x_in;  srow = base; }
    else          { src = x_mem; srow = base - R; }

    // W column -> 14 float4 = 56 VGPRs (statically indexed)
    float4 w4[14];
    #pragma unroll
    for (int q = 0; q < 14; ++q)
        w4[q] = ((const float4*)(conv_w + h * LFEAT))[q];

    // fold BN: f = dot*sc + sh
    const float sc = gamma[h] / sqrtf(bvar[h] + 1e-5f);
    const float sh = (conv_b[h] - bmean[h]) * sc + beta[h];

    #pragma unroll 1
    for (int r = 0; r < FROWS; ++r) {
        const float4* xrow = (const float4*)(src + (long)(srow + r) * LFEAT);
        float a0 = 0.0f, a1 = 0.0f;         // two chains over even/odd q
        #pragma unroll
        for (int q = 0; q < 14; q += 2) {
            const float4 xa = xrow[q];
            const float4 xb = xrow[q + 1];
            a0 = fmaf(xa.x, w4[q].x, a0);     a0 = fmaf(xa.y, w4[q].y, a0);
            a0 = fmaf(xa.z, w4[q].z, a0);     a0 = fmaf(xa.w, w4[q].w, a0);
            a1 = fmaf(xb.x, w4[q + 1].x, a1); a1 = fmaf(xb.y, w4[q + 1].y, a1);
            a1 = fmaf(xb.z, w4[q + 1].z, a1); a1 = fmaf(xb.w, w4[q + 1].w, a1);
        }
        float f = (a0 + a1) * sc + sh;
        f = (f >= 0.0f) ? f : 0.1f * f;      // LeakyReLU(0.1)
        f_all[(long)(base + r) * HFEAT + h] = f;   // coalesced over h
    }
}

// ---------------------------------------------------------------------------
// Kernel B (unchanged from round 11): banded attention, LDS-staged f_mem band.
// ---------------------------------------------------------------------------
__global__ __launch_bounds__(512) void attn_kernel(
    const float* __restrict__ f_all,
    const float* __restrict__ x_in, const float* __restrict__ x_mem,
    float* __restrict__ out, int R)
{
    __shared__ float fs[BAND][LDW];         // 48 x 132 floats = 25.3 KB

    const int tid  = threadIdx.x;
    const int wave = tid >> 6;              // 0..7
    const int lane = tid & 63;

    const int chunks = NPTS / BR;           // 64
    const int b      = blockIdx.x / chunks;
    const int c0     = (blockIdx.x - b * chunks) * BR;
    const int bbase  = b * NPTS;

    // ---- stage f_mem band (coalesced; 32 float4 per row)
    for (int i = tid; i < BAND * 32; i += 512) {
        const int r = i >> 5;
        const int q = i & 31;
        const int g = min(max(c0 - HALFW + r, 0), NPTS - 1);
        const float4 v = ((const float4*)(f_all + (long)(R + bbase + g) * HFEAT))[q];
        *((float4*)&fs[r][4 * q]) = v;
    }
    __syncthreads();

    const int lh = lane & 31;               // lane within 32-half

    #pragma unroll
    for (int rr = 0; rr < 4; rr += 2) {
        const int nA  = c0 + wave * 4 + rr;          // half 0's row (in batch)
        const int n   = nA + (lane >> 5);            // this half's row
        const int row = bbase + n;

        // ---- QK on lanes lh < 17 of each half
        const int  mw    = n - HALFW + lh;
        const int  mc    = min(max(mw, 0), NPTS - 1);
        const int  slot  = mc - c0 + HALFW;          // LDS band slot
        const bool valid = (lh < NEIGH) && (mw >= 0) && (mw < NPTS);

        float p = -1e30f;
        if (lh < NEIGH) {
            const float4* fin = (const float4*)(f_all + (long)row * HFEAT); // half-uniform
            const float4* fm  = (const float4*)&fs[slot][0];
            float4 a0 = {0.f,0.f,0.f,0.f}, a1 = {0.f,0.f,0.f,0.f};
            #pragma unroll
            for (int q = 0; q < 32; q += 2) {
                const float4 xi0 = fin[q],     xm0 = fm[q];
                const float4 xi1 = fin[q + 1], xm1 = fm[q + 1];
                a0.x = fmaf(xi0.x, xm0.x, a0.x); a0.y = fmaf(xi0.y, xm0.y, a0.y);
                a0.z = fmaf(xi0.z, xm0.z, a0.z); a0.w = fmaf(xi0.w, xm0.w, a0.w);
                a1.x = fmaf(xi1.x, xm1.x, a1.x); a1.y = fmaf(xi1.y, xm1.y, a1.y);
                a1.z = fmaf(xi1.z, xm1.z, a1.z); a1.w = fmaf(xi1.w, xm1.w, a1.w);
            }
            p = ((a0.x + a0.y) + (a0.z + a0.w)) + ((a1.x + a1.y) + (a1.z + a1.w));
            p = valid ? p : -1e30f;
        }

        // ---- softmax within each 32-half (invalid lanes: exp -> 0)
        float mx = p;
        #pragma unroll
        for (int off = 16; off >= 1; off >>= 1)
            mx = fmaxf(mx, __shfl_xor(mx, off));
        const float e = expf(p - mx);
        float sum = e;
        #pragma unroll
        for (int off = 16; off >= 1; off >>= 1)
            sum += __shfl_xor(sum, off);
        const float pn = e / sum;

        // ---- broadcast weights for both rows (compile-time lane -> readlane)
        float swA[NEIGH], swB[NEIGH];
        #pragma unroll
        for (int w = 0; w < NEIGH; ++w) {
            swA[w] = __shfl(pn, w);
            swB[w] = __shfl(pn, 32 + w);
        }

        // ---- PV + blend, lanes 0..55, both rows
        if (lane < LFEAT) {
            const float* memb = x_mem + (long)bbase * LFEAT;

            float accA = 0.0f, accB = 0.0f;
            #pragma unroll
            for (int w = 0; w < NEIGH; ++w) {
                const int mA = min(max(nA     - HALFW + w, 0), NPTS - 1);
                const int mB = min(max(nA + 1 - HALFW + w, 0), NPTS - 1);
                accA = fmaf(swA[w], memb[(long)mA * LFEAT + lane], accA);
                accB = fmaf(swB[w], memb[(long)mB * LFEAT + lane], accB);
            }
            const long oA = (long)(bbase + nA) * LFEAT + lane;
            const long oB = oA + LFEAT;
            out[oA] = 0.5f * x_in[oA] + 0.5f * accA;
            out[oB] = 0.5f * x_in[oB] + 0.5f * accB;
        }
    }
}

// ---------------------------------------------------------------------------
extern "C" void kernel_launch(void* const* d_in, const int* in_sizes, int n_in,
                              void* d_out, int out_size, void* d_ws, size_t ws_size,
                              hipStream_t stream)
{
    const float* input  = (const float*)d_in[0];
    const float* smem   = (const float*)d_in[1];
    const float* conv_w = (const float*)d_in[2];
    const float* conv_b = (const float*)d_in[3];
    const float* gamma  = (const float*)d_in[4];
    const float* beta   = (const float*)d_in[5];
    const float* bmean  = (const float*)d_in[6];
    const float* bvar   = (const float*)d_in[7];
    float* out = (float*)d_out;

    const int R = in_sizes[0] / LFEAT;   // B*N = 16384
    float* f_all = (float*)d_ws;         // 2*R*128 floats = 16 MB

    const int blocksA = (2 * R) / FROWS;   // 2048 blocks, 128 threads
    feat_kernel<<<blocksA, 128, 0, stream>>>(input, smem, conv_w, conv_b,
                                             gamma, beta, bmean, bvar, f_all, R);

    const int blocksB = (R / NPTS) * (NPTS / BR);   // B * 64 = 512 blocks
    attn_kernel<<<blocksB, 512, 0, stream>>>(f_all, input, smem, out, R);
}

// Round 13
// 101.424 us; speedup vs baseline: 1.1813x; 1.1813x over previous
//
#include <hip/hip_runtime.h>
#include <math.h>

#define NPTS   2048      // N
#define LFEAT  56        // C*L
#define HFEAT  128       // H
#define HALFW  8
#define NEIGH  17
#define BR     32        // rows per block (chunk within one batch)
#define BAND   48        // BR + 2*HALFW
#define LDW    132       // f-row pad: 132 floats (528B, 16B-aligned rows)

// ---------------------------------------------------------------------------
// Fully fused: per block (32 rows of one batch):
//  1. stage raw x_mem band (48 rows) + x_in chunk (32 rows) into LDS
//  2. compute f = LeakyReLU(BN(conv(x))) for band (f_mem) and chunk (f_in)
//     into LDS; W column lives in 56 VGPRs; x read as LDS broadcast
//  3. banded attention: QK from LDS, 5+5 shfl_xor softmax per 32-half,
//     PV from the SAME staged x_mem band, blend, store.
// No f_all round-trip, single launch.
// ---------------------------------------------------------------------------
__global__ __launch_bounds__(512) void fused_kernel(
    const float* __restrict__ x_in, const float* __restrict__ x_mem,
    const float* __restrict__ conv_w, const float* __restrict__ conv_b,
    const float* __restrict__ gamma,  const float* __restrict__ beta,
    const float* __restrict__ bmean,  const float* __restrict__ bvar,
    float* __restrict__ out, int R)
{
    __shared__ float4 xm4[BAND * 14];      // raw x_mem band  (10.5 KB)
    __shared__ float4 xi4[BR * 14];        // raw x_in chunk  ( 7.0 KB)
    __shared__ float  fm[BAND][LDW];       // f_mem band      (25.3 KB)
    __shared__ float  fi[BR][LDW];         // f_in chunk      (16.9 KB)

    const int tid    = threadIdx.x;
    const int chunks = NPTS / BR;          // 64
    const int b      = blockIdx.x / chunks;
    const int c0     = (blockIdx.x - b * chunks) * BR;
    const int bbase  = b * NPTS;

    // ---- 1. stage raw x (coalesced float4)
    const float4* srcm = (const float4*)(x_mem + (long)bbase * LFEAT);
    for (int i = tid; i < BAND * 14; i += 512) {
        const int r = i / 14, q = i - r * 14;
        const int g = min(max(c0 - HALFW + r, 0), NPTS - 1);
        xm4[i] = srcm[g * 14 + q];
    }
    const float4* srci = (const float4*)(x_in + (long)(bbase + c0) * LFEAT);
    for (int i = tid; i < BR * 14; i += 512) xi4[i] = srci[i];

    // ---- W column (56 VGPRs) + BN fold (overlaps staging)
    const int h  = tid & 127;
    const int rg = tid >> 7;               // 0..3
    float4 w4[14];
    #pragma unroll
    for (int q = 0; q < 14; ++q)
        w4[q] = ((const float4*)(conv_w + h * LFEAT))[q];
    const float sc = gamma[h] / sqrtf(bvar[h] + 1e-5f);
    const float sh = (conv_b[h] - bmean[h]) * sc + beta[h];

    __syncthreads();

    // ---- 2. features (x rows read as wave-uniform LDS broadcast)
    for (int r = rg; r < BAND; r += 4) {   // 12 rows/thread
        const float4* xr = &xm4[r * 14];
        float a0 = 0.0f, a1 = 0.0f;
        #pragma unroll
        for (int q = 0; q < 14; q += 2) {
            const float4 xa = xr[q], xb = xr[q + 1];
            a0 = fmaf(xa.x, w4[q].x, a0);     a0 = fmaf(xa.y, w4[q].y, a0);
            a0 = fmaf(xa.z, w4[q].z, a0);     a0 = fmaf(xa.w, w4[q].w, a0);
            a1 = fmaf(xb.x, w4[q + 1].x, a1); a1 = fmaf(xb.y, w4[q + 1].y, a1);
            a1 = fmaf(xb.z, w4[q + 1].z, a1); a1 = fmaf(xb.w, w4[q + 1].w, a1);
        }
        float f = (a0 + a1) * sc + sh;
        fm[r][h] = (f >= 0.0f) ? f : 0.1f * f;
    }
    for (int r = rg; r < BR; r += 4) {     // 8 rows/thread
        const float4* xr = &xi4[r * 14];
        float a0 = 0.0f, a1 = 0.0f;
        #pragma unroll
        for (int q = 0; q < 14; q += 2) {
            const float4 xa = xr[q], xb = xr[q + 1];
            a0 = fmaf(xa.x, w4[q].x, a0);     a0 = fmaf(xa.y, w4[q].y, a0);
            a0 = fmaf(xa.z, w4[q].z, a0);     a0 = fmaf(xa.w, w4[q].w, a0);
            a1 = fmaf(xb.x, w4[q + 1].x, a1); a1 = fmaf(xb.y, w4[q + 1].y, a1);
            a1 = fmaf(xb.z, w4[q + 1].z, a1); a1 = fmaf(xb.w, w4[q + 1].w, a1);
        }
        float f = (a0 + a1) * sc + sh;
        fi[r][h] = (f >= 0.0f) ? f : 0.1f * f;
    }
    __syncthreads();

    // ---- 3. banded attention (wave: 4 rows, 2 per pass, one per 32-half)
    const int wave = tid >> 6;
    const int lane = tid & 63;
    const int lh   = lane & 31;
    const float* xmf = (const float*)xm4;  // band as floats [BAND*56]
    const float* xif = (const float*)xi4;  // chunk as floats [BR*56]

    #pragma unroll
    for (int rr = 0; rr < 4; rr += 2) {
        const int l0   = wave * 4 + rr;            // local row, half 0
        const int lrow = l0 + (lane >> 5);         // this half's local row
        const int n    = c0 + lrow;                // row within batch

        // QK on lanes lh < 17 of each half
        const int  mw    = n - HALFW + lh;
        const int  mc    = min(max(mw, 0), NPTS - 1);
        const int  slot  = mc - c0 + HALFW;        // LDS band slot
        const bool valid = (lh < NEIGH) && (mw >= 0) && (mw < NPTS);

        float p = -1e30f;
        if (lh < NEIGH) {
            const float4* a  = (const float4*)&fi[lrow][0];  // half-uniform
            const float4* bb = (const float4*)&fm[slot][0];  // per-lane
            float4 A0 = {0.f,0.f,0.f,0.f}, A1 = {0.f,0.f,0.f,0.f};
            #pragma unroll
            for (int q = 0; q < 32; q += 2) {
                const float4 u0 = a[q],     v0 = bb[q];
                const float4 u1 = a[q + 1], v1 = bb[q + 1];
                A0.x = fmaf(u0.x, v0.x, A0.x); A0.y = fmaf(u0.y, v0.y, A0.y);
                A0.z = fmaf(u0.z, v0.z, A0.z); A0.w = fmaf(u0.w, v0.w, A0.w);
                A1.x = fmaf(u1.x, v1.x, A1.x); A1.y = fmaf(u1.y, v1.y, A1.y);
                A1.z = fmaf(u1.z, v1.z, A1.z); A1.w = fmaf(u1.w, v1.w, A1.w);
            }
            const float d = ((A0.x + A0.y) + (A0.z + A0.w))
                          + ((A1.x + A1.y) + (A1.z + A1.w));
            p = valid ? d : -1e30f;
        }

        // softmax within each 32-half (invalid lanes contribute exp -> 0)
        float mx = p;
        #pragma unroll
        for (int off = 16; off >= 1; off >>= 1)
            mx = fmaxf(mx, __shfl_xor(mx, off));
        const float e = expf(p - mx);
        float sum = e;
        #pragma unroll
        for (int off = 16; off >= 1; off >>= 1)
            sum += __shfl_xor(sum, off);
        const float pn = e / sum;

        // broadcast weights for both rows (compile-time lane -> v_readlane)
        float swA[NEIGH], swB[NEIGH];
        #pragma unroll
        for (int w = 0; w < NEIGH; ++w) {
            swA[w] = __shfl(pn, w);
            swB[w] = __shfl(pn, 32 + w);
        }

        // PV from the staged raw x_mem band + blend; lanes 0..55
        if (lane < LFEAT) {
            float accA = 0.0f, accB = 0.0f;
            #pragma unroll
            for (int w = 0; w < NEIGH; ++w) {
                const int sA = min(max(c0 + l0     - HALFW + w, 0), NPTS - 1) - c0 + HALFW;
                const int sB = min(max(c0 + l0 + 1 - HALFW + w, 0), NPTS - 1) - c0 + HALFW;
                accA = fmaf(swA[w], xmf[sA * LFEAT + lane], accA);
                accB = fmaf(swB[w], xmf[sB * LFEAT + lane], accB);
            }
            const long oA = (long)(bbase + c0 + l0) * LFEAT + lane;
            out[oA]         = 0.5f * xif[ l0      * LFEAT + lane] + 0.5f * accA;
            out[oA + LFEAT] = 0.5f * xif[(l0 + 1) * LFEAT + lane] + 0.5f * accB;
        }
    }
}

// ---------------------------------------------------------------------------
extern "C" void kernel_launch(void* const* d_in, const int* in_sizes, int n_in,
                              void* d_out, int out_size, void* d_ws, size_t ws_size,
                              hipStream_t stream)
{
    const float* input  = (const float*)d_in[0];
    const float* smem   = (const float*)d_in[1];
    const float* conv_w = (const float*)d_in[2];
    const float* conv_b = (const float*)d_in[3];
    const float* gamma  = (const float*)d_in[4];
    const float* beta   = (const float*)d_in[5];
    const float* bmean  = (const float*)d_in[6];
    const float* bvar   = (const float*)d_in[7];
    float* out = (float*)d_out;

    const int R = in_sizes[0] / LFEAT;              // B*N = 16384
    const int blocks = (R / NPTS) * (NPTS / BR);    // 8 * 64 = 512

    fused_kernel<<<blocks, 512, 0, stream>>>(input, smem, conv_w, conv_b,
                                             gamma, beta, bmean, bvar, out, R);
}